// Round 5
// baseline (463.514 us; speedup 1.0000x reference)
//
#include <hip/hip_runtime.h>

typedef unsigned short u16;
typedef __attribute__((ext_vector_type(8))) short short8;
typedef __attribute__((ext_vector_type(4))) float f32x4;

constexpr int B_ = 2;
constexpr int H_ = 8;
constexpr int KVH_ = 4;
constexpr int S_ = 2048;
constexpr int D_ = 256;
constexpr int HID_ = 2304;
constexpr int QKVN_ = 4096;   // 2048 q + 1024 k + 1024 v
constexpr int AON_ = 2048;    // H_*D_

__device__ __forceinline__ float b2f(u16 u) {
  union { float f; unsigned int i; } x; x.i = ((unsigned int)u) << 16; return x.f;
}
__device__ __forceinline__ u16 f2b(float f) {
  unsigned int x = __float_as_uint(f);
  unsigned int r = (x + 0x7fffu + ((x >> 16) & 1u)) >> 16;
  return (u16)r;
}

// ---------------- cast fp32 -> bf16 (vectorized) ----------------
__global__ void cast_kernel(const float* __restrict__ in, u16* __restrict__ out) {
  size_t i = ((size_t)blockIdx.x * 256 + threadIdx.x) * 4;
  float4 v = *(const float4*)(in + i);
  unsigned int lo = (unsigned int)f2b(v.x) | ((unsigned int)f2b(v.y) << 16);
  unsigned int hi = (unsigned int)f2b(v.z) | ((unsigned int)f2b(v.w) << 16);
  uint2 o; o.x = lo; o.y = hi;
  *(uint2*)(out + i) = o;
}

// ---------------- transpose + cast: src (R x C) fp32 -> dst (C x R) bf16 ----------------
__global__ void transpose_cast(const float* __restrict__ src, u16* __restrict__ dst,
                               int R, int C) {
  __shared__ float tile[64][65];
  int r0 = blockIdx.y * 64, c0 = blockIdx.x * 64;
  int t = threadIdx.x;
#pragma unroll
  for (int i = 0; i < 16; ++i) {
    int e = i * 256 + t;
    int r = e >> 6, c = e & 63;
    tile[r][c] = src[(size_t)(r0 + r) * C + (c0 + c)];
  }
  __syncthreads();
#pragma unroll
  for (int i = 0; i < 16; ++i) {
    int e = i * 256 + t;
    int orow = e >> 6, ocol = e & 63;
    dst[(size_t)(c0 + orow) * R + (r0 + ocol)] = f2b(tile[ocol][orow]);
  }
}

// ---------------- m97-style bf16 GEMM: C = A(MxK) * B^T where B is (N x K) ----------------
template <int OUTF32>
__global__ __launch_bounds__(256, 2) void gemm_bt(
    const u16* __restrict__ A, const u16* __restrict__ B, void* __restrict__ Cp,
    int M, int N, int K) {
  __shared__ u16 As[128 * 32];
  __shared__ u16 Bs[128 * 32];
  int m0 = blockIdx.y * 128, n0 = blockIdx.x * 128;
  int tid = threadIdx.x;
  int lane = tid & 63, wave = tid >> 6;
  int wy = wave >> 1, wx = wave & 1;
  int quad = lane >> 4, l16 = lane & 15;
  f32x4 acc[4][4] = {};
  for (int k0 = 0; k0 < K; k0 += 32) {
#pragma unroll
    for (int i = 0; i < 2; ++i) {
      int chunk = i * 256 + tid;
      int row = chunk >> 2, col = (chunk & 3) << 3;
      __builtin_amdgcn_global_load_lds(
          (const __attribute__((address_space(1))) void*)(A + (size_t)(m0 + row) * K + k0 + col),
          (__attribute__((address_space(3))) void*)(As + chunk * 8), 16, 0, 0);
    }
#pragma unroll
    for (int i = 0; i < 2; ++i) {
      int chunk = i * 256 + tid;
      int row = chunk >> 2, col = (chunk & 3) << 3;
      __builtin_amdgcn_global_load_lds(
          (const __attribute__((address_space(1))) void*)(B + (size_t)(n0 + row) * K + k0 + col),
          (__attribute__((address_space(3))) void*)(Bs + chunk * 8), 16, 0, 0);
    }
    __syncthreads();
    short8 af[4], bf[4];
#pragma unroll
    for (int mi = 0; mi < 4; ++mi)
      af[mi] = *(const short8*)(As + (wy * 64 + mi * 16 + l16) * 32 + quad * 8);
#pragma unroll
    for (int ni = 0; ni < 4; ++ni)
      bf[ni] = *(const short8*)(Bs + (wx * 64 + ni * 16 + l16) * 32 + quad * 8);
#pragma unroll
    for (int mi = 0; mi < 4; ++mi)
#pragma unroll
      for (int ni = 0; ni < 4; ++ni)
        acc[mi][ni] = __builtin_amdgcn_mfma_f32_16x16x32_bf16(af[mi], bf[ni], acc[mi][ni], 0, 0, 0);
    __syncthreads();
  }
#pragma unroll
  for (int mi = 0; mi < 4; ++mi) {
#pragma unroll
    for (int ni = 0; ni < 4; ++ni) {
#pragma unroll
      for (int r = 0; r < 4; ++r) {
        int row = m0 + wy * 64 + mi * 16 + quad * 4 + r;
        int col = n0 + wx * 64 + ni * 16 + l16;
        if (OUTF32)
          ((float*)Cp)[(size_t)row * N + col] = acc[mi][ni][r];
        else
          ((u16*)Cp)[(size_t)row * N + col] = f2b(acc[mi][ni][r]);
      }
    }
  }
}

// ---------------- RoPE + rearrange: qkv (4096 x 4096) -> Q (B,H,S,D), K (B,KVH,S,D) ----------------
__global__ void rope_kernel(const u16* __restrict__ qkv, const float* __restrict__ cs,
                            const float* __restrict__ sn, u16* __restrict__ Qr,
                            u16* __restrict__ Kr) {
  int row = blockIdx.x;          // b*S + s
  int b = row >> 11, s = row & 2047;
  int d = threadIdx.x;           // 0..255
  const u16* qrow = qkv + (size_t)row * QKVN_;
  float c = cs[(size_t)row * D_ + d];
  float si = sn[(size_t)row * D_ + d];
  int dp = (d < 128) ? d + 128 : d - 128;
  float sgn = (d < 128) ? -1.f : 1.f;
#pragma unroll
  for (int h = 0; h < H_; ++h) {
    float v = b2f(qrow[h * D_ + d]);
    float p = sgn * b2f(qrow[h * D_ + dp]);
    Qr[((size_t)(b * H_ + h) * S_ + s) * D_ + d] = f2b(v * c + p * si);
  }
#pragma unroll
  for (int g = 0; g < KVH_; ++g) {
    float v = b2f(qrow[2048 + g * D_ + d]);
    float p = sgn * b2f(qrow[2048 + g * D_ + dp]);
    Kr[((size_t)(b * KVH_ + g) * S_ + s) * D_ + d] = f2b(v * c + p * si);
  }
}

// ---------------- V transpose: qkv v-part -> Vt (B,KVH,D,S) ----------------
__global__ void transpose_v(const u16* __restrict__ qkv, u16* __restrict__ Vt) {
  __shared__ u16 tile[64][72];
  int d0 = blockIdx.x * 64, s0 = blockIdx.y * 64, g = blockIdx.z; // g = b*KVH+kvh
  int b = g >> 2, kvh = g & 3;
  int t = threadIdx.x;
#pragma unroll
  for (int i = 0; i < 16; ++i) {
    int e = i * 256 + t;
    int r = e >> 6, c = e & 63;
    tile[r][c] = qkv[(size_t)(b * S_ + s0 + r) * QKVN_ + 3072 + kvh * D_ + d0 + c];
  }
  __syncthreads();
#pragma unroll
  for (int i = 0; i < 16; ++i) {
    int e = i * 256 + t;
    int orow = e >> 6, ocol = e & 63;
    Vt[((size_t)g * D_ + d0 + orow) * S_ + s0 + ocol] = tile[ocol][orow];
  }
}

// ---------------- flash attention v5 ----------------
// v4 was latency-bound at 2 blocks/CU (grid 512 was the occupancy cap;
// OccupancyPercent stuck at 12.5% with short-block tails). v5: 32-row q-tiles,
// 128-thread (2-wave) blocks -> grid (64,8,2) = 1024 blocks = 4 blocks/CU.
// Per-wave resources unchanged (16 q-rows, o_acc 64 VGPR) -> no spills.
// LDS/block 35.3 KB -> 4 blocks = 141 KB <= 160. Balance: qt = b==0 ? 63-bx : bx
// -> each CU's 4 round-robin blocks are 2x(64-bx) + 2x(bx+1) = 130 iters const.
__global__ __launch_bounds__(128, 4) void attn_kernel(
    const u16* __restrict__ Qr, const u16* __restrict__ Kr, const u16* __restrict__ Vt,
    u16* __restrict__ Ao) {
  __shared__ u16 Ks[32 * 256];   // 16 KB: 32 keys x 256 d, chunk-swizzled (^ key&7)
  __shared__ u16 Vs[256 * 32];   // 16 KB: 256 d x 32 keys, chunk-swizzled (^ (d>>1)&3)
  __shared__ u16 Ps[2][16 * 40]; // 2.5 KB: wave-private P relayout scratch
  int b = blockIdx.z;
  int qt = (b == 0) ? (63 - blockIdx.x) : blockIdx.x;  // balanced pairing per CU
  int h = blockIdx.y;
  int kvh = h >> 1;  // N_REP = 2
  int tid = threadIdx.x, wave = tid >> 6, lane = tid & 63;
  int quad = lane >> 4, l16 = lane & 15;
  int q0w = qt * 32 + wave * 16;  // this wave's first q row
  // Q fragments in registers: A-layout m=l16, k=quad*8+j
  const u16* Qbase = Qr + ((size_t)(b * H_ + h) * S_ + q0w + l16) * D_;
  short8 qf[8];
#pragma unroll
  for (int kk = 0; kk < 8; ++kk)
    qf[kk] = *(const short8*)(Qbase + kk * 32 + quad * 8);
  const u16* Kbase = Kr + (size_t)(b * KVH_ + kvh) * S_ * D_;
  const u16* Vbase = Vt + (size_t)(b * KVH_ + kvh) * D_ * S_;
  float l_r[4] = {0.f, 0.f, 0.f, 0.f};
  f32x4 o_acc[16] = {};
  int nkt = qt + 1;  // 32-key tiles
  for (int kt = 0; kt < nkt; ++kt) {
    int k0 = kt * 32;
    __syncthreads();  // all waves done reading prev K/V tile
    // stage K tile: 16 KB, 8 chunks/thread, chunk-swizzled source
#pragma unroll
    for (int i = 0; i < 8; ++i) {
      int p = i * 128 + tid;
      int s = p >> 5, pc = p & 31;
      int c = pc ^ (s & 7);
      __builtin_amdgcn_global_load_lds(
          (const __attribute__((address_space(1))) void*)(Kbase + (size_t)(k0 + s) * D_ + c * 8),
          (__attribute__((address_space(3))) void*)(Ks + p * 8), 16, 0, 0);
    }
    // stage V tile: 16 KB (rows of 32 keys), chunk-swizzled source
#pragma unroll
    for (int i = 0; i < 8; ++i) {
      int p = i * 128 + tid;
      int d = p >> 2, ps = p & 3;
      int sl = ps ^ ((d >> 1) & 3);
      __builtin_amdgcn_global_load_lds(
          (const __attribute__((address_space(1))) void*)(Vbase + (size_t)d * S_ + k0 + sl * 8),
          (__attribute__((address_space(3))) void*)(Vs + p * 8), 16, 0, 0);
    }
    __syncthreads();  // staged (compiler inserts vmcnt(0) before barrier)
    // S = Q K^T : 2 key sub-tiles of 16
    f32x4 sacc[2] = {};
#pragma unroll
    for (int n = 0; n < 2; ++n) {
      int srow = n * 16 + l16;
      const u16* kb = Ks + srow * 256;
      int sw = l16 & 7;
#pragma unroll
      for (int kk = 0; kk < 8; ++kk) {
        int phys = (kk * 4 + quad) ^ sw;
        short8 bfr = *(const short8*)(kb + phys * 8);
        sacc[n] = __builtin_amdgcn_mfma_f32_16x16x32_bf16(qf[kk], bfr, sacc[n], 0, 0, 0);
      }
    }
    // fused softcap+softmax: ee = exp(50*tanh(s/16/50) - 50) = exp(-100/(E+1)),
    // E = exp(sacc * 0.0025). Fixed max (softcap bounds s at +50).
    float rs[4] = {0.f, 0.f, 0.f, 0.f};
    bool full = (k0 + 31 <= q0w);  // wave-uniform: no masking needed
#pragma unroll
    for (int n = 0; n < 2; ++n) {
      int key = k0 + n * 16 + l16;
#pragma unroll
      for (int r = 0; r < 4; ++r) {
        float E = __expf(sacc[n][r] * 0.0025f);
        float ee = __expf(-100.0f * __frcp_rn(E + 1.0f));
        if (!full) {
          int qq = q0w + quad * 4 + r;
          ee = (key <= qq) ? ee : 0.0f;
        }
        rs[r] += ee;
        Ps[wave][(quad * 4 + r) * 40 + n * 16 + l16] = f2b(ee);
      }
    }
#pragma unroll
    for (int off = 1; off < 16; off <<= 1)
#pragma unroll
      for (int r = 0; r < 4; ++r)
        rs[r] += __shfl_xor(rs[r], off, 64);
#pragma unroll
    for (int r = 0; r < 4; ++r) l_r[r] += rs[r];
    // O += P V  (P read back in A-layout; wave-private, no barrier needed)
    short8 pa = *(const short8*)(&Ps[wave][l16 * 40 + quad * 8]);
#pragma unroll
    for (int dt = 0; dt < 16; ++dt) {
      int d = dt * 16 + l16;
      int phys = quad ^ ((d >> 1) & 3);
      short8 vb = *(const short8*)(Vs + d * 32 + phys * 8);
      o_acc[dt] = __builtin_amdgcn_mfma_f32_16x16x32_bf16(pa, vb, o_acc[dt], 0, 0, 0);
    }
  }
#pragma unroll
  for (int r = 0; r < 4; ++r) l_r[r] = 1.0f / l_r[r];
#pragma unroll
  for (int dt = 0; dt < 16; ++dt)
#pragma unroll
    for (int r = 0; r < 4; ++r) {
      int row = b * S_ + q0w + quad * 4 + r;
      int col = h * D_ + dt * 16 + l16;
      Ao[(size_t)row * AON_ + col] = f2b(o_acc[dt][r] * l_r[r]);
    }
}

extern "C" void kernel_launch(void* const* d_in, const int* in_sizes, int n_in,
                              void* d_out, int out_size, void* d_ws, size_t ws_size,
                              hipStream_t stream) {
  const float* hidden = (const float*)d_in[0];
  const float* cosp = (const float*)d_in[1];
  const float* sinp = (const float*)d_in[2];
  // d_in[3] = attention_mask: exactly causal 0/-1e9 -> handled analytically
  const float* Wq = (const float*)d_in[4];
  const float* Wk = (const float*)d_in[5];
  const float* Wv = (const float*)d_in[6];
  const float* Wo = (const float*)d_in[7];

  u16* hs  = (u16*)d_ws;                              // 4096 x 2304
  u16* WT  = hs  + (size_t)4096 * HID_;               // 4096 x 2304  ([Wq|Wk|Wv]^T)
  u16* WoT = WT  + (size_t)4096 * HID_;               // 2304 x 2048
  u16* qkv = WoT + (size_t)HID_ * AON_;               // 4096 x 4096
  u16* Qr  = qkv + (size_t)4096 * QKVN_;              // B,H,S,D
  u16* Kr  = Qr  + (size_t)B_ * H_ * S_ * D_;         // B,KVH,S,D
  u16* Vt  = Kr  + (size_t)B_ * KVH_ * S_ * D_;       // B,KVH,D,S
  u16* Ao  = Vt  + (size_t)B_ * KVH_ * S_ * D_;       // 4096 x 2048

  cast_kernel<<<9216, 256, 0, stream>>>(hidden, hs);
  transpose_cast<<<dim3(32, 36), 256, 0, stream>>>(Wq, WT, HID_, 2048);
  transpose_cast<<<dim3(16, 36), 256, 0, stream>>>(Wk, WT + (size_t)2048 * HID_, HID_, 1024);
  transpose_cast<<<dim3(16, 36), 256, 0, stream>>>(Wv, WT + (size_t)3072 * HID_, HID_, 1024);
  transpose_cast<<<dim3(36, 32), 256, 0, stream>>>(Wo, WoT, 2048, HID_);
  gemm_bt<0><<<dim3(32, 32), 256, 0, stream>>>(hs, WT, qkv, 4096, QKVN_, HID_);
  rope_kernel<<<4096, 256, 0, stream>>>(qkv, cosp, sinp, Qr, Kr);
  transpose_v<<<dim3(4, 32, 8), 256, 0, stream>>>(qkv, Vt);
  attn_kernel<<<dim3(64, 8, 2), 128, 0, stream>>>(Qr, Kr, Vt, Ao);
  gemm_bt<1><<<dim3(18, 32), 256, 0, stream>>>(Ao, WoT, d_out, 4096, HID_, 2048);
}

// Round 6
// 441.205 us; speedup vs baseline: 1.0506x; 1.0506x over previous
//
#include <hip/hip_runtime.h>

typedef unsigned short u16;
typedef __attribute__((ext_vector_type(8))) short short8;
typedef __attribute__((ext_vector_type(4))) float f32x4;

constexpr int B_ = 2;
constexpr int H_ = 8;
constexpr int KVH_ = 4;
constexpr int S_ = 2048;
constexpr int D_ = 256;
constexpr int HID_ = 2304;
constexpr int QKVN_ = 4096;   // 2048 q + 1024 k + 1024 v
constexpr int AON_ = 2048;    // H_*D_

__device__ __forceinline__ float b2f(u16 u) {
  union { float f; unsigned int i; } x; x.i = ((unsigned int)u) << 16; return x.f;
}
__device__ __forceinline__ u16 f2b(float f) {
  unsigned int x = __float_as_uint(f);
  unsigned int r = (x + 0x7fffu + ((x >> 16) & 1u)) >> 16;
  return (u16)r;
}

// ---------------- cast fp32 -> bf16 (vectorized) ----------------
__global__ void cast_kernel(const float* __restrict__ in, u16* __restrict__ out) {
  size_t i = ((size_t)blockIdx.x * 256 + threadIdx.x) * 4;
  float4 v = *(const float4*)(in + i);
  unsigned int lo = (unsigned int)f2b(v.x) | ((unsigned int)f2b(v.y) << 16);
  unsigned int hi = (unsigned int)f2b(v.z) | ((unsigned int)f2b(v.w) << 16);
  uint2 o; o.x = lo; o.y = hi;
  *(uint2*)(out + i) = o;
}

// ---------------- transpose + cast: src (R x C) fp32 -> dst (C x R) bf16 ----------------
__global__ void transpose_cast(const float* __restrict__ src, u16* __restrict__ dst,
                               int R, int C) {
  __shared__ float tile[64][65];
  int r0 = blockIdx.y * 64, c0 = blockIdx.x * 64;
  int t = threadIdx.x;
#pragma unroll
  for (int i = 0; i < 16; ++i) {
    int e = i * 256 + t;
    int r = e >> 6, c = e & 63;
    tile[r][c] = src[(size_t)(r0 + r) * C + (c0 + c)];
  }
  __syncthreads();
#pragma unroll
  for (int i = 0; i < 16; ++i) {
    int e = i * 256 + t;
    int orow = e >> 6, ocol = e & 63;
    dst[(size_t)(c0 + orow) * R + (r0 + ocol)] = f2b(tile[ocol][orow]);
  }
}

// ---------------- m97-style bf16 GEMM: C = A(MxK) * B^T where B is (N x K) ----------------
template <int OUTF32>
__global__ __launch_bounds__(256, 2) void gemm_bt(
    const u16* __restrict__ A, const u16* __restrict__ B, void* __restrict__ Cp,
    int M, int N, int K) {
  __shared__ u16 As[128 * 32];
  __shared__ u16 Bs[128 * 32];
  int m0 = blockIdx.y * 128, n0 = blockIdx.x * 128;
  int tid = threadIdx.x;
  int lane = tid & 63, wave = tid >> 6;
  int wy = wave >> 1, wx = wave & 1;
  int quad = lane >> 4, l16 = lane & 15;
  f32x4 acc[4][4] = {};
  for (int k0 = 0; k0 < K; k0 += 32) {
#pragma unroll
    for (int i = 0; i < 2; ++i) {
      int chunk = i * 256 + tid;
      int row = chunk >> 2, col = (chunk & 3) << 3;
      __builtin_amdgcn_global_load_lds(
          (const __attribute__((address_space(1))) void*)(A + (size_t)(m0 + row) * K + k0 + col),
          (__attribute__((address_space(3))) void*)(As + chunk * 8), 16, 0, 0);
    }
#pragma unroll
    for (int i = 0; i < 2; ++i) {
      int chunk = i * 256 + tid;
      int row = chunk >> 2, col = (chunk & 3) << 3;
      __builtin_amdgcn_global_load_lds(
          (const __attribute__((address_space(1))) void*)(B + (size_t)(n0 + row) * K + k0 + col),
          (__attribute__((address_space(3))) void*)(Bs + chunk * 8), 16, 0, 0);
    }
    __syncthreads();
    short8 af[4], bf[4];
#pragma unroll
    for (int mi = 0; mi < 4; ++mi)
      af[mi] = *(const short8*)(As + (wy * 64 + mi * 16 + l16) * 32 + quad * 8);
#pragma unroll
    for (int ni = 0; ni < 4; ++ni)
      bf[ni] = *(const short8*)(Bs + (wx * 64 + ni * 16 + l16) * 32 + quad * 8);
#pragma unroll
    for (int mi = 0; mi < 4; ++mi)
#pragma unroll
      for (int ni = 0; ni < 4; ++ni)
        acc[mi][ni] = __builtin_amdgcn_mfma_f32_16x16x32_bf16(af[mi], bf[ni], acc[mi][ni], 0, 0, 0);
    __syncthreads();
  }
#pragma unroll
  for (int mi = 0; mi < 4; ++mi) {
#pragma unroll
    for (int ni = 0; ni < 4; ++ni) {
#pragma unroll
      for (int r = 0; r < 4; ++r) {
        int row = m0 + wy * 64 + mi * 16 + quad * 4 + r;
        int col = n0 + wx * 64 + ni * 16 + l16;
        if (OUTF32)
          ((float*)Cp)[(size_t)row * N + col] = acc[mi][ni][r];
        else
          ((u16*)Cp)[(size_t)row * N + col] = f2b(acc[mi][ni][r]);
      }
    }
  }
}

// ---------------- RoPE + rearrange: qkv (4096 x 4096) -> Q (B,H,S,D), K (B,KVH,S,D) ----------------
__global__ void rope_kernel(const u16* __restrict__ qkv, const float* __restrict__ cs,
                            const float* __restrict__ sn, u16* __restrict__ Qr,
                            u16* __restrict__ Kr) {
  int row = blockIdx.x;          // b*S + s
  int b = row >> 11, s = row & 2047;
  int d = threadIdx.x;           // 0..255
  const u16* qrow = qkv + (size_t)row * QKVN_;
  float c = cs[(size_t)row * D_ + d];
  float si = sn[(size_t)row * D_ + d];
  int dp = (d < 128) ? d + 128 : d - 128;
  float sgn = (d < 128) ? -1.f : 1.f;
#pragma unroll
  for (int h = 0; h < H_; ++h) {
    float v = b2f(qrow[h * D_ + d]);
    float p = sgn * b2f(qrow[h * D_ + dp]);
    Qr[((size_t)(b * H_ + h) * S_ + s) * D_ + d] = f2b(v * c + p * si);
  }
#pragma unroll
  for (int g = 0; g < KVH_; ++g) {
    float v = b2f(qrow[2048 + g * D_ + d]);
    float p = sgn * b2f(qrow[2048 + g * D_ + dp]);
    Kr[((size_t)(b * KVH_ + g) * S_ + s) * D_ + d] = f2b(v * c + p * si);
  }
}

// ---------------- V transpose: qkv v-part -> Vt (B,KVH,D,S) ----------------
__global__ void transpose_v(const u16* __restrict__ qkv, u16* __restrict__ Vt) {
  __shared__ u16 tile[64][72];
  int d0 = blockIdx.x * 64, s0 = blockIdx.y * 64, g = blockIdx.z; // g = b*KVH+kvh
  int b = g >> 2, kvh = g & 3;
  int t = threadIdx.x;
#pragma unroll
  for (int i = 0; i < 16; ++i) {
    int e = i * 256 + t;
    int r = e >> 6, c = e & 63;
    tile[r][c] = qkv[(size_t)(b * S_ + s0 + r) * QKVN_ + 3072 + kvh * D_ + d0 + c];
  }
  __syncthreads();
#pragma unroll
  for (int i = 0; i < 16; ++i) {
    int e = i * 256 + t;
    int orow = e >> 6, ocol = e & 63;
    Vt[((size_t)g * D_ + d0 + orow) * S_ + s0 + ocol] = tile[ocol][orow];
  }
}

// ---------------- flash attention v6 ----------------
// v4 (best: 132us, launch_bounds(256,2), 64-row q-tiles, grid (32,8,2)) was
// ~60% exposed staging latency: lockstep stage->barrier->compute->barrier.
// v6: DOUBLE-BUFFERED K/V. Issue global_load_lds for tile kt+1 into buf^1 at
// top of iter kt, compute tile kt from buf, ONE __syncthreads per iter (the
// compiler's vmcnt(0) drain before the barrier is free: loads were issued a
// full compute-body (~1500cyc) earlier, >> L2 latency). Buffer reuse is safe:
// writes to buf^1 happen only after the barrier ending the iter that last
// read buf^1. Also hoisted the 16-lane softmax-sum reduction out of the
// k-loop (per-lane partials, one reduction at the end: -32 shfl+add/iter).
// LDS 69KB -> 2 blocks/CU (138KB <= 160KB).
__global__ __launch_bounds__(256, 2) void attn_kernel(
    const u16* __restrict__ Qr, const u16* __restrict__ Kr, const u16* __restrict__ Vt,
    u16* __restrict__ Ao) {
  __shared__ u16 Ks[2][32 * 256]; // 2x16 KB: 32 keys x 256 d, chunk-swizzled (^ key&7)
  __shared__ u16 Vs[2][32 * 256]; // 2x16 KB: 256 d x 32 keys, chunk-swizzled (^ (d>>1)&3)
  __shared__ u16 Ps[4][16 * 40];  // 5 KB: wave-private P relayout scratch
  int b = blockIdx.z;
  int qt = (b == 0) ? (31 - blockIdx.x) : blockIdx.x;  // balanced pairing per CU
  int h = blockIdx.y;
  int kvh = h >> 1;  // N_REP = 2
  int tid = threadIdx.x, wave = tid >> 6, lane = tid & 63;
  int quad = lane >> 4, l16 = lane & 15;
  int q0 = qt * 64;
  // Q fragments in registers: wave owns q rows [q0+wave*16, +16); A-layout m=l16, k=quad*8+j
  const u16* Qbase = Qr + ((size_t)(b * H_ + h) * S_ + q0 + wave * 16 + l16) * D_;
  short8 qf[8];
#pragma unroll
  for (int kk = 0; kk < 8; ++kk)
    qf[kk] = *(const short8*)(Qbase + kk * 32 + quad * 8);
  const u16* Kbase = Kr + (size_t)(b * KVH_ + kvh) * S_ * D_;
  const u16* Vbase = Vt + (size_t)(b * KVH_ + kvh) * D_ * S_;
  // precomputed staging addresses (thread-invariant across iters except k0)
  int ksrc_s[4], ksrc_c[4], vsrc_d[4], vsrc_s[4];
#pragma unroll
  for (int i = 0; i < 4; ++i) {
    int p = i * 256 + tid;
    ksrc_s[i] = p >> 5;
    ksrc_c[i] = (p & 31) ^ ((p >> 5) & 7);
    vsrc_d[i] = p >> 2;
    vsrc_s[i] = (p & 3) ^ ((p >> 3) & 3);  // (d>>1)&3 with d=p>>2 -> (p>>3)&3
  }
  float lp[4] = {0.f, 0.f, 0.f, 0.f};
  f32x4 o_acc[16] = {};
  int nkt = 2 * qt + 2;  // 32-key tiles

#define STAGE(KT, BUF)                                                                   \
  {                                                                                      \
    int k0s = (KT) * 32;                                                                 \
    _Pragma("unroll") for (int i = 0; i < 4; ++i) {                                      \
      int p = i * 256 + tid;                                                             \
      __builtin_amdgcn_global_load_lds(                                                  \
          (const __attribute__((address_space(1))) void*)(Kbase +                        \
              (size_t)(k0s + ksrc_s[i]) * D_ + ksrc_c[i] * 8),                           \
          (__attribute__((address_space(3))) void*)(&Ks[BUF][0] + p * 8), 16, 0, 0);     \
    }                                                                                    \
    _Pragma("unroll") for (int i = 0; i < 4; ++i) {                                      \
      int p = i * 256 + tid;                                                             \
      __builtin_amdgcn_global_load_lds(                                                  \
          (const __attribute__((address_space(1))) void*)(Vbase +                        \
              (size_t)vsrc_d[i] * S_ + k0s + vsrc_s[i] * 8),                             \
          (__attribute__((address_space(3))) void*)(&Vs[BUF][0] + p * 8), 16, 0, 0);     \
    }                                                                                    \
  }

  STAGE(0, 0);
  __syncthreads();  // tile 0 staged
  for (int kt = 0; kt < nkt; ++kt) {
    int k0 = kt * 32;
    int cur = kt & 1;
    if (kt + 1 < nkt) STAGE(kt + 1, cur ^ 1);  // prefetch next tile (in-flight during compute)
    // S = Q K^T : 2 key sub-tiles of 16
    f32x4 sacc[2] = {};
#pragma unroll
    for (int n = 0; n < 2; ++n) {
      int srow = n * 16 + l16;
      const u16* kb = &Ks[cur][0] + srow * 256;
      int sw = l16 & 7;
#pragma unroll
      for (int kk = 0; kk < 8; ++kk) {
        int phys = (kk * 4 + quad) ^ sw;
        short8 bfr = *(const short8*)(kb + phys * 8);
        sacc[n] = __builtin_amdgcn_mfma_f32_16x16x32_bf16(qf[kk], bfr, sacc[n], 0, 0, 0);
      }
    }
    // fused softcap+softmax: ee = exp(50*tanh(s/16/50) - 50) = exp(-100/(E+1)),
    // E = exp(sacc * 0.0025). Fixed max (softcap bounds s at +50).
    bool full = (k0 + 31 <= q0 + wave * 16);  // wave-uniform: no masking needed
#pragma unroll
    for (int n = 0; n < 2; ++n) {
      int key = k0 + n * 16 + l16;
#pragma unroll
      for (int r = 0; r < 4; ++r) {
        float E = __expf(sacc[n][r] * 0.0025f);
        float ee = __expf(-100.0f * __frcp_rn(E + 1.0f));
        if (!full) {
          int qq = q0 + wave * 16 + quad * 4 + r;
          ee = (key <= qq) ? ee : 0.0f;
        }
        lp[r] += ee;  // per-lane partial; reduced once after the loop
        Ps[wave][(quad * 4 + r) * 40 + n * 16 + l16] = f2b(ee);
      }
    }
    // O += P V  (P read back in A-layout; wave-private, no barrier needed)
    short8 pa = *(const short8*)(&Ps[wave][l16 * 40 + quad * 8]);
#pragma unroll
    for (int dt = 0; dt < 16; ++dt) {
      int d = dt * 16 + l16;
      int phys = quad ^ ((d >> 1) & 3);
      short8 vb = *(const short8*)(&Vs[cur][0] + d * 32 + phys * 8);
      o_acc[dt] = __builtin_amdgcn_mfma_f32_16x16x32_bf16(pa, vb, o_acc[dt], 0, 0, 0);
    }
    __syncthreads();  // end of iter: next-tile loads long since landed; buffer handoff
  }
#undef STAGE
  // one softmax-denominator reduction across the 16 key-lanes
#pragma unroll
  for (int off = 1; off < 16; off <<= 1)
#pragma unroll
    for (int r = 0; r < 4; ++r)
      lp[r] += __shfl_xor(lp[r], off, 64);
#pragma unroll
  for (int r = 0; r < 4; ++r) lp[r] = 1.0f / lp[r];
#pragma unroll
  for (int dt = 0; dt < 16; ++dt)
#pragma unroll
    for (int r = 0; r < 4; ++r) {
      int row = b * S_ + q0 + wave * 16 + quad * 4 + r;
      int col = h * D_ + dt * 16 + l16;
      Ao[(size_t)row * AON_ + col] = f2b(o_acc[dt][r] * lp[r]);
    }
}

extern "C" void kernel_launch(void* const* d_in, const int* in_sizes, int n_in,
                              void* d_out, int out_size, void* d_ws, size_t ws_size,
                              hipStream_t stream) {
  const float* hidden = (const float*)d_in[0];
  const float* cosp = (const float*)d_in[1];
  const float* sinp = (const float*)d_in[2];
  // d_in[3] = attention_mask: exactly causal 0/-1e9 -> handled analytically
  const float* Wq = (const float*)d_in[4];
  const float* Wk = (const float*)d_in[5];
  const float* Wv = (const float*)d_in[6];
  const float* Wo = (const float*)d_in[7];

  u16* hs  = (u16*)d_ws;                              // 4096 x 2304
  u16* WT  = hs  + (size_t)4096 * HID_;               // 4096 x 2304  ([Wq|Wk|Wv]^T)
  u16* WoT = WT  + (size_t)4096 * HID_;               // 2304 x 2048
  u16* qkv = WoT + (size_t)HID_ * AON_;               // 4096 x 4096
  u16* Qr  = qkv + (size_t)4096 * QKVN_;              // B,H,S,D
  u16* Kr  = Qr  + (size_t)B_ * H_ * S_ * D_;         // B,KVH,S,D
  u16* Vt  = Kr  + (size_t)B_ * KVH_ * S_ * D_;       // B,KVH,D,S
  u16* Ao  = Vt  + (size_t)B_ * KVH_ * S_ * D_;       // 4096 x 2048

  cast_kernel<<<9216, 256, 0, stream>>>(hidden, hs);
  transpose_cast<<<dim3(32, 36), 256, 0, stream>>>(Wq, WT, HID_, 2048);
  transpose_cast<<<dim3(16, 36), 256, 0, stream>>>(Wk, WT + (size_t)2048 * HID_, HID_, 1024);
  transpose_cast<<<dim3(16, 36), 256, 0, stream>>>(Wv, WT + (size_t)3072 * HID_, HID_, 1024);
  transpose_cast<<<dim3(36, 32), 256, 0, stream>>>(Wo, WoT, 2048, HID_);
  gemm_bt<0><<<dim3(32, 32), 256, 0, stream>>>(hs, WT, qkv, 4096, QKVN_, HID_);
  rope_kernel<<<4096, 256, 0, stream>>>(qkv, cosp, sinp, Qr, Kr);
  transpose_v<<<dim3(4, 32, 8), 256, 0, stream>>>(qkv, Vt);
  attn_kernel<<<dim3(32, 8, 2), 256, 0, stream>>>(Qr, Kr, Vt, Ao);
  gemm_bt<1><<<dim3(18, 32), 256, 0, stream>>>(Ao, WoT, d_out, 4096, HID_, 2048);
}

// Round 7
// 427.571 us; speedup vs baseline: 1.0841x; 1.0319x over previous
//
#include <hip/hip_runtime.h>

typedef unsigned short u16;
typedef __attribute__((ext_vector_type(8))) short short8;
typedef __attribute__((ext_vector_type(4))) float f32x4;

constexpr int B_ = 2;
constexpr int H_ = 8;
constexpr int KVH_ = 4;
constexpr int S_ = 2048;
constexpr int D_ = 256;
constexpr int HID_ = 2304;
constexpr int QKVN_ = 4096;   // 2048 q + 1024 k + 1024 v
constexpr int AON_ = 2048;    // H_*D_

__device__ __forceinline__ float b2f(u16 u) {
  union { float f; unsigned int i; } x; x.i = ((unsigned int)u) << 16; return x.f;
}
__device__ __forceinline__ u16 f2b(float f) {
  unsigned int x = __float_as_uint(f);
  unsigned int r = (x + 0x7fffu + ((x >> 16) & 1u)) >> 16;
  return (u16)r;
}

// ---------------- cast fp32 -> bf16 (vectorized) ----------------
__global__ void cast_kernel(const float* __restrict__ in, u16* __restrict__ out) {
  size_t i = ((size_t)blockIdx.x * 256 + threadIdx.x) * 4;
  float4 v = *(const float4*)(in + i);
  unsigned int lo = (unsigned int)f2b(v.x) | ((unsigned int)f2b(v.y) << 16);
  unsigned int hi = (unsigned int)f2b(v.z) | ((unsigned int)f2b(v.w) << 16);
  uint2 o; o.x = lo; o.y = hi;
  *(uint2*)(out + i) = o;
}

// ---------------- all 4 weight transposes in ONE launch ----------------
// z: 0=Wq(2304x2048) 1=Wk(2304x1024) 2=Wv(2304x1024) 3=Wo(2048x2304)
__global__ void transpose_cast_all(const float* __restrict__ s0, const float* __restrict__ s1,
                                   const float* __restrict__ s2, const float* __restrict__ s3,
                                   u16* __restrict__ d0, u16* __restrict__ d1,
                                   u16* __restrict__ d2, u16* __restrict__ d3) {
  __shared__ float tile[64][65];
  int which = blockIdx.z;
  const float* src; u16* dst; int R, C;
  if (which == 0)      { src = s0; dst = d0; R = 2304; C = 2048; }
  else if (which == 1) { src = s1; dst = d1; R = 2304; C = 1024; }
  else if (which == 2) { src = s2; dst = d2; R = 2304; C = 1024; }
  else                 { src = s3; dst = d3; R = 2048; C = 2304; }
  int r0 = blockIdx.y * 64, c0 = blockIdx.x * 64;
  if (r0 >= R || c0 >= C) return;
  int t = threadIdx.x;
#pragma unroll
  for (int i = 0; i < 16; ++i) {
    int e = i * 256 + t;
    int r = e >> 6, c = e & 63;
    tile[r][c] = src[(size_t)(r0 + r) * C + (c0 + c)];
  }
  __syncthreads();
#pragma unroll
  for (int i = 0; i < 16; ++i) {
    int e = i * 256 + t;
    int orow = e >> 6, ocol = e & 63;
    dst[(size_t)(c0 + orow) * R + (r0 + ocol)] = f2b(tile[ocol][orow]);
  }
}

// ---------------- m97-style bf16 GEMM: C = A(MxK) * B^T where B is (N x K) ----------------
template <int OUTF32>
__global__ __launch_bounds__(256, 2) void gemm_bt(
    const u16* __restrict__ A, const u16* __restrict__ B, void* __restrict__ Cp,
    int M, int N, int K) {
  __shared__ u16 As[128 * 32];
  __shared__ u16 Bs[128 * 32];
  int m0 = blockIdx.y * 128, n0 = blockIdx.x * 128;
  int tid = threadIdx.x;
  int lane = tid & 63, wave = tid >> 6;
  int wy = wave >> 1, wx = wave & 1;
  int quad = lane >> 4, l16 = lane & 15;
  f32x4 acc[4][4] = {};
  for (int k0 = 0; k0 < K; k0 += 32) {
#pragma unroll
    for (int i = 0; i < 2; ++i) {
      int chunk = i * 256 + tid;
      int row = chunk >> 2, col = (chunk & 3) << 3;
      __builtin_amdgcn_global_load_lds(
          (const __attribute__((address_space(1))) void*)(A + (size_t)(m0 + row) * K + k0 + col),
          (__attribute__((address_space(3))) void*)(As + chunk * 8), 16, 0, 0);
    }
#pragma unroll
    for (int i = 0; i < 2; ++i) {
      int chunk = i * 256 + tid;
      int row = chunk >> 2, col = (chunk & 3) << 3;
      __builtin_amdgcn_global_load_lds(
          (const __attribute__((address_space(1))) void*)(B + (size_t)(n0 + row) * K + k0 + col),
          (__attribute__((address_space(3))) void*)(Bs + chunk * 8), 16, 0, 0);
    }
    __syncthreads();
    short8 af[4], bf[4];
#pragma unroll
    for (int mi = 0; mi < 4; ++mi)
      af[mi] = *(const short8*)(As + (wy * 64 + mi * 16 + l16) * 32 + quad * 8);
#pragma unroll
    for (int ni = 0; ni < 4; ++ni)
      bf[ni] = *(const short8*)(Bs + (wx * 64 + ni * 16 + l16) * 32 + quad * 8);
#pragma unroll
    for (int mi = 0; mi < 4; ++mi)
#pragma unroll
      for (int ni = 0; ni < 4; ++ni)
        acc[mi][ni] = __builtin_amdgcn_mfma_f32_16x16x32_bf16(af[mi], bf[ni], acc[mi][ni], 0, 0, 0);
    __syncthreads();
  }
#pragma unroll
  for (int mi = 0; mi < 4; ++mi) {
#pragma unroll
    for (int ni = 0; ni < 4; ++ni) {
#pragma unroll
      for (int r = 0; r < 4; ++r) {
        int row = m0 + wy * 64 + mi * 16 + quad * 4 + r;
        int col = n0 + wx * 64 + ni * 16 + l16;
        if (OUTF32)
          ((float*)Cp)[(size_t)row * N + col] = acc[mi][ni][r];
        else
          ((u16*)Cp)[(size_t)row * N + col] = f2b(acc[mi][ni][r]);
      }
    }
  }
}

// ---------------- RoPE + rearrange: qkv (4096 x 4096) -> Q (B,H,S,D), K (B,KVH,S,D) ----------------
__global__ void rope_kernel(const u16* __restrict__ qkv, const float* __restrict__ cs,
                            const float* __restrict__ sn, u16* __restrict__ Qr,
                            u16* __restrict__ Kr) {
  int row = blockIdx.x;          // b*S + s
  int b = row >> 11, s = row & 2047;
  int d = threadIdx.x;           // 0..255
  const u16* qrow = qkv + (size_t)row * QKVN_;
  float c = cs[(size_t)row * D_ + d];
  float si = sn[(size_t)row * D_ + d];
  int dp = (d < 128) ? d + 128 : d - 128;
  float sgn = (d < 128) ? -1.f : 1.f;
#pragma unroll
  for (int h = 0; h < H_; ++h) {
    float v = b2f(qrow[h * D_ + d]);
    float p = sgn * b2f(qrow[h * D_ + dp]);
    Qr[((size_t)(b * H_ + h) * S_ + s) * D_ + d] = f2b(v * c + p * si);
  }
#pragma unroll
  for (int g = 0; g < KVH_; ++g) {
    float v = b2f(qrow[2048 + g * D_ + d]);
    float p = sgn * b2f(qrow[2048 + g * D_ + dp]);
    Kr[((size_t)(b * KVH_ + g) * S_ + s) * D_ + d] = f2b(v * c + p * si);
  }
}

// ---------------- V transpose: qkv v-part -> Vt (B,KVH,D,S) ----------------
__global__ void transpose_v(const u16* __restrict__ qkv, u16* __restrict__ Vt) {
  __shared__ u16 tile[64][72];
  int d0 = blockIdx.x * 64, s0 = blockIdx.y * 64, g = blockIdx.z; // g = b*KVH+kvh
  int b = g >> 2, kvh = g & 3;
  int t = threadIdx.x;
#pragma unroll
  for (int i = 0; i < 16; ++i) {
    int e = i * 256 + t;
    int r = e >> 6, c = e & 63;
    tile[r][c] = qkv[(size_t)(b * S_ + s0 + r) * QKVN_ + 3072 + kvh * D_ + d0 + c];
  }
  __syncthreads();
#pragma unroll
  for (int i = 0; i < 16; ++i) {
    int e = i * 256 + t;
    int orow = e >> 6, ocol = e & 63;
    Vt[((size_t)g * D_ + d0 + orow) * S_ + s0 + ocol] = tile[ocol][orow];
  }
}

// ---------------- flash attention v7: uniform-length 2-way split-K ----------------
// v6's "balanced-sum" pairing left a (64,4)-iter pair per CU: 94% of the time only
// one block resident (Occupancy 12%). v7: every block runs EXACTLY 33 tile-iters:
// part A = (b=0, qt=u, key-half s), part B = (b=1, qt=31-u, key-half s), x=2u+s.
// Fixed-max softmax => split partials combine linearly: O = O0+O1, l = l0+l1.
// Partials: fp32 O per split (aliases dead ws: hs+WT region / qkv region) + l.
// Dbuf K/V staging kept from v6. Combine kernel normalizes -> bf16 Ao.
__global__ __launch_bounds__(256, 2) void attn_kernel(
    const u16* __restrict__ Qr, const u16* __restrict__ Kr, const u16* __restrict__ Vt,
    float* __restrict__ Op0, float* __restrict__ Op1,
    float* __restrict__ Lp0, float* __restrict__ Lp1) {
  __shared__ u16 Ks[2][32 * 256]; // 2x16 KB, chunk-swizzled (^ key&7)
  __shared__ u16 Vs[2][32 * 256]; // 2x16 KB, chunk-swizzled (^ (d>>1)&3)
  __shared__ u16 Ps[4][16 * 40];  // 5 KB: wave-private P relayout scratch
  int u = blockIdx.x >> 1, sp = blockIdx.x & 1;
  int h = blockIdx.y;
  int kvh = h >> 1;  // N_REP = 2
  int tid = threadIdx.x, wave = tid >> 6, lane = tid & 63;
  int quad = lane >> 4, l16 = lane & 15;
  float* Op = sp ? Op1 : Op0;
  float* Lp = sp ? Lp1 : Lp0;
  // precomputed staging address pieces
  int ksrc_s[4], ksrc_c[4], vsrc_d[4], vsrc_s[4];
#pragma unroll
  for (int i = 0; i < 4; ++i) {
    int p = i * 256 + tid;
    ksrc_s[i] = p >> 5;
    ksrc_c[i] = (p & 31) ^ ((p >> 5) & 7);
    vsrc_d[i] = p >> 2;
    vsrc_s[i] = (p & 3) ^ ((p >> 3) & 3);
  }

  for (int part = 0; part < 2; ++part) {
    int b = part;
    int qt = (part == 0) ? u : (31 - u);
    int q0 = qt * 64;
    int beg = sp ? (qt + 1) : 0;          // key-half split: [0,qt+1) or [qt+1,2qt+2)
    int end = sp ? (2 * qt + 2) : (qt + 1);
    const u16* Qbase = Qr + ((size_t)(b * H_ + h) * S_ + q0 + wave * 16 + l16) * D_;
    short8 qf[8];
#pragma unroll
    for (int kk = 0; kk < 8; ++kk)
      qf[kk] = *(const short8*)(Qbase + kk * 32 + quad * 8);
    const u16* Kbase = Kr + (size_t)(b * KVH_ + kvh) * S_ * D_;
    const u16* Vbase = Vt + (size_t)(b * KVH_ + kvh) * D_ * S_;
    float lp[4] = {0.f, 0.f, 0.f, 0.f};
    f32x4 o_acc[16] = {};

#define STAGE(KT, BUF)                                                                   \
    {                                                                                    \
      int k0s = (KT) * 32;                                                               \
      _Pragma("unroll") for (int i = 0; i < 4; ++i) {                                    \
        int p = i * 256 + tid;                                                           \
        __builtin_amdgcn_global_load_lds(                                                \
            (const __attribute__((address_space(1))) void*)(Kbase +                      \
                (size_t)(k0s + ksrc_s[i]) * D_ + ksrc_c[i] * 8),                         \
            (__attribute__((address_space(3))) void*)(&Ks[BUF][0] + p * 8), 16, 0, 0);   \
      }                                                                                  \
      _Pragma("unroll") for (int i = 0; i < 4; ++i) {                                    \
        int p = i * 256 + tid;                                                           \
        __builtin_amdgcn_global_load_lds(                                                \
            (const __attribute__((address_space(1))) void*)(Vbase +                      \
                (size_t)vsrc_d[i] * S_ + k0s + vsrc_s[i] * 8),                           \
            (__attribute__((address_space(3))) void*)(&Vs[BUF][0] + p * 8), 16, 0, 0);   \
      }                                                                                  \
    }

    STAGE(beg, 0);
    __syncthreads();  // first tile staged (safe vs prev part: loop-end barrier passed)
    for (int kt = beg; kt < end; ++kt) {
      int k0 = kt * 32;
      int cur = (kt - beg) & 1;
      if (kt + 1 < end) STAGE(kt + 1, cur ^ 1);  // prefetch in-flight during compute
      // S = Q K^T : 2 key sub-tiles of 16
      f32x4 sacc[2] = {};
#pragma unroll
      for (int n = 0; n < 2; ++n) {
        int srow = n * 16 + l16;
        const u16* kb = &Ks[cur][0] + srow * 256;
        int sw = l16 & 7;
#pragma unroll
        for (int kk = 0; kk < 8; ++kk) {
          int phys = (kk * 4 + quad) ^ sw;
          short8 bfr = *(const short8*)(kb + phys * 8);
          sacc[n] = __builtin_amdgcn_mfma_f32_16x16x32_bf16(qf[kk], bfr, sacc[n], 0, 0, 0);
        }
      }
      // fused softcap+softmax: ee = exp(50*tanh(s/16/50)-50) = exp(-100/(E+1)), E=exp(s*0.0025)
      bool full = (k0 + 31 <= q0 + wave * 16);  // wave-uniform
#pragma unroll
      for (int n = 0; n < 2; ++n) {
        int key = k0 + n * 16 + l16;
#pragma unroll
        for (int r = 0; r < 4; ++r) {
          float E = __expf(sacc[n][r] * 0.0025f);
          float ee = __expf(-100.0f * __frcp_rn(E + 1.0f));
          if (!full) {
            int qq = q0 + wave * 16 + quad * 4 + r;
            ee = (key <= qq) ? ee : 0.0f;
          }
          lp[r] += ee;
          Ps[wave][(quad * 4 + r) * 40 + n * 16 + l16] = f2b(ee);
        }
      }
      // O += P V  (wave-private Ps, no barrier)
      short8 pa = *(const short8*)(&Ps[wave][l16 * 40 + quad * 8]);
#pragma unroll
      for (int dt = 0; dt < 16; ++dt) {
        int d = dt * 16 + l16;
        int phys = quad ^ ((d >> 1) & 3);
        short8 vb = *(const short8*)(&Vs[cur][0] + d * 32 + phys * 8);
        o_acc[dt] = __builtin_amdgcn_mfma_f32_16x16x32_bf16(pa, vb, o_acc[dt], 0, 0, 0);
      }
      __syncthreads();  // buffer handoff (prefetch long since landed)
    }
#undef STAGE
    // denominator partial: reduce across the 16 key-lanes
#pragma unroll
    for (int off = 1; off < 16; off <<= 1)
#pragma unroll
      for (int r = 0; r < 4; ++r)
        lp[r] += __shfl_xor(lp[r], off, 64);
    if (l16 == 0) {
#pragma unroll
      for (int r = 0; r < 4; ++r)
        Lp[((size_t)(b * H_ + h)) * S_ + q0 + wave * 16 + quad * 4 + r] = lp[r];
    }
    // unnormalized fp32 partial O
#pragma unroll
    for (int dt = 0; dt < 16; ++dt)
#pragma unroll
      for (int r = 0; r < 4; ++r) {
        int row = b * S_ + q0 + wave * 16 + quad * 4 + r;
        int col = h * D_ + dt * 16 + l16;
        Op[(size_t)row * AON_ + col] = o_acc[dt][r];
      }
  }
}

// ---------------- combine splits: Ao = (O0+O1) / (l0+l1), bf16 ----------------
__global__ void combine_kernel(const float* __restrict__ Op0, const float* __restrict__ Op1,
                               const float* __restrict__ Lp0, const float* __restrict__ Lp1,
                               u16* __restrict__ Ao) {
  size_t idx = (size_t)blockIdx.x * 256 + threadIdx.x;  // one float4 per thread
  size_t row = idx >> 9;            // 512 float4 per row (2048 cols)
  int c4 = ((int)idx & 511) * 4;
  const float4 a = *(const float4*)(Op0 + row * AON_ + c4);
  const float4 b4 = *(const float4*)(Op1 + row * AON_ + c4);
  int b = (int)(row >> 11), s = (int)row & 2047;
  int h = c4 >> 8;
  size_t li = ((size_t)(b * H_ + h)) * S_ + s;
  float inv = 1.0f / (Lp0[li] + Lp1[li]);
  unsigned int lo = (unsigned int)f2b((a.x + b4.x) * inv) | ((unsigned int)f2b((a.y + b4.y) * inv) << 16);
  unsigned int hi = (unsigned int)f2b((a.z + b4.z) * inv) | ((unsigned int)f2b((a.w + b4.w) * inv) << 16);
  uint2 o; o.x = lo; o.y = hi;
  *(uint2*)(Ao + row * AON_ + c4) = o;
}

extern "C" void kernel_launch(void* const* d_in, const int* in_sizes, int n_in,
                              void* d_out, int out_size, void* d_ws, size_t ws_size,
                              hipStream_t stream) {
  const float* hidden = (const float*)d_in[0];
  const float* cosp = (const float*)d_in[1];
  const float* sinp = (const float*)d_in[2];
  // d_in[3] = attention_mask: exactly causal 0/-1e9 -> handled analytically
  const float* Wq = (const float*)d_in[4];
  const float* Wk = (const float*)d_in[5];
  const float* Wv = (const float*)d_in[6];
  const float* Wo = (const float*)d_in[7];

  u16* hs  = (u16*)d_ws;                              // 4096 x 2304 (dead after gemm1)
  u16* WT  = hs  + (size_t)4096 * HID_;               // 4096 x 2304 (dead after gemm1)
  u16* WoT = WT  + (size_t)4096 * HID_;               // 2304 x 2048 (live till gemm2)
  u16* qkv = WoT + (size_t)HID_ * AON_;               // 4096 x 4096 (dead after rope/transpose_v)
  u16* Qr  = qkv + (size_t)4096 * QKVN_;              // B,H,S,D
  u16* Kr  = Qr  + (size_t)B_ * H_ * S_ * D_;         // B,KVH,S,D
  u16* Vt  = Kr  + (size_t)B_ * KVH_ * S_ * D_;       // B,KVH,D,S
  u16* Ao  = Vt  + (size_t)B_ * KVH_ * S_ * D_;       // 4096 x 2048
  float* Lp0 = (float*)(Ao + (size_t)4096 * AON_);    // 2*8*2048 fp32
  float* Lp1 = Lp0 + (size_t)B_ * H_ * S_;            // 2*8*2048 fp32
  // split-K O partials alias DEAD regions (fp32 4096x2048 = 33.5 MB each):
  float* Op0 = (float*)hs;    // hs+WT region: 37.7 MB available >= 33.5
  float* Op1 = (float*)qkv;   // qkv region: 33.5 MB, exact fit

  cast_kernel<<<9216, 256, 0, stream>>>(hidden, hs);
  transpose_cast_all<<<dim3(36, 36, 4), 256, 0, stream>>>(
      Wq, Wk, Wv, Wo, WT, WT + (size_t)2048 * HID_, WT + (size_t)3072 * HID_, WoT);
  gemm_bt<0><<<dim3(32, 32), 256, 0, stream>>>(hs, WT, qkv, 4096, QKVN_, HID_);
  rope_kernel<<<4096, 256, 0, stream>>>(qkv, cosp, sinp, Qr, Kr);
  transpose_v<<<dim3(4, 32, 8), 256, 0, stream>>>(qkv, Vt);
  attn_kernel<<<dim3(64, 8), 256, 0, stream>>>(Qr, Kr, Vt, Op0, Op1, Lp0, Lp1);
  combine_kernel<<<16384, 256, 0, stream>>>(Op0, Op1, Lp0, Lp1, Ao);
  gemm_bt<1><<<dim3(18, 32), 256, 0, stream>>>(Ao, WoT, d_out, 4096, HID_, 2048);
}